// Round 7
// baseline (146.719 us; speedup 1.0000x reference)
//
#include <hip/hip_runtime.h>

namespace {

constexpr int NV = 512;
constexpr unsigned WMAX = 0xFFFFFFFFu;
typedef unsigned long long ull;
constexpr ull INF64 = ~0ULL;

// Edge total order = reference's stable sort: (f32 weight bits, triu index).
// triu index is order-isomorphic to lex (i,j), i<j, so the canonical key
// (w_bits<<32)|(i<<9)|j induces the identical order (w>=0 -> bits monotone).
// Keys globally unique -> unique MST -> Boruvka (contracted or not) accepts
// exactly Kruskal's edge set; all combining is via min -> deterministic.

// packed upper-tri index for dense pair a<b (C<=128): idx = a*(253-a)/2 + b - 1
__device__ __forceinline__ int packIdx(unsigned a, unsigned b) {
    return (int)((a * (253u - a)) >> 1) + (int)b - 1;
}

__global__ __launch_bounds__(1024) void boruvka_loss(
    const float* __restrict__ d1, const float* __restrict__ d2,
    float* __restrict__ partial)
{
    const int blk = blockIdx.x;
    const float* __restrict__ Dm = blk ? d2 : d1;
    const float* __restrict__ Do = blk ? d1 : d2;
    const int tid = threadIdx.x;
    const int lane = tid & 63;
    const int wid = tid >> 6;

    __shared__ ull R[8128];                       // packed comp-pair min keys (63.5 KB)
    __shared__ __align__(16) unsigned comp[NV];   // vertex -> comp (roots), then dense id
    __shared__ unsigned bestW[NV];                // rounds 0-1; reused as dense map
    __shared__ unsigned bestLo[NV];
    __shared__ unsigned parent[NV];               // also reused as present[] flags
    __shared__ ull bestK[128];                    // later rounds: per-comp best key
    __shared__ unsigned cc[128];                  // dense id -> current comp (dense id)
    __shared__ unsigned cpar[128];
    __shared__ unsigned waveSum[8];
    __shared__ int waveAcc[8];
    __shared__ float red[17];
    __shared__ int accTot, doneFlag;

    if (tid < NV) { comp[tid] = tid; bestW[tid] = WMAX; bestLo[tid] = WMAX; }
    if (tid == 0) { accTot = 0; doneFlag = 0; }

    const int v  = tid >> 1;               // 2 threads per row
    const int c0 = (tid & 1) << 8;         // column half 0 / 256
    const float4* __restrict__ rowp4 =
        reinterpret_cast<const float4*>(Dm + ((size_t)v << 9) + c0);
    const uint4* comp4 = reinterpret_cast<const uint4*>(&comp[c0]);
    const int sEx = ((v & 256) == c0) ? ((v & 255) >> 2) : -1;  // diagonal group
    const int kEx = v & 3;

    float contrib  = 0.f;   // rounds 0-1 (all threads)
    float contrib2 = 0.f;   // later rounds (wave 0 lanes)

    __syncthreads();

    // ================= rounds 0,1: vertex-level =================
    for (int round = 0; round < 2; ++round) {
        unsigned cv;
        unsigned wmin = WMAX;
        int smin = 0;
        if (round == 0) {
            cv = (unsigned)v;
#pragma unroll 8
            for (int s = 0; s < 64; ++s) {
                float4 w4 = rowp4[s];
                unsigned m0 = __float_as_uint(w4.x);
                unsigned m1 = __float_as_uint(w4.y);
                unsigned m2 = __float_as_uint(w4.z);
                unsigned m3 = __float_as_uint(w4.w);
                if (s == sEx) {
                    if (kEx == 0) m0 = WMAX;
                    if (kEx == 1) m1 = WMAX;
                    if (kEx == 2) m2 = WMAX;
                    if (kEx == 3) m3 = WMAX;
                }
                unsigned t = min(min(m0, m1), min(m2, m3));
                if (t < wmin) { wmin = t; smin = s; }
            }
        } else {
            cv = comp[v];
#pragma unroll 8
            for (int s = 0; s < 64; ++s) {
                float4 w4 = rowp4[s];
                uint4  q4 = comp4[s];
                unsigned m0 = (q4.x != cv) ? __float_as_uint(w4.x) : WMAX;
                unsigned m1 = (q4.y != cv) ? __float_as_uint(w4.y) : WMAX;
                unsigned m2 = (q4.z != cv) ? __float_as_uint(w4.z) : WMAX;
                unsigned m3 = (q4.w != cv) ? __float_as_uint(w4.w) : WMAX;
                unsigned t = min(min(m0, m1), min(m2, m3));
                if (t < wmin) { wmin = t; smin = s; }
            }
        }
        if (wmin != WMAX && bestW[cv] > wmin) atomicMin(&bestW[cv], wmin);
        __syncthreads();

        // tie-break index among weight winners
        if (wmin != WMAX && wmin == bestW[cv]) {
            float4 w4 = rowp4[smin];
            unsigned m0, m1, m2, m3;
            if (round == 0) {
                m0 = __float_as_uint(w4.x); m1 = __float_as_uint(w4.y);
                m2 = __float_as_uint(w4.z); m3 = __float_as_uint(w4.w);
                if (smin == sEx) {
                    if (kEx == 0) m0 = WMAX;
                    if (kEx == 1) m1 = WMAX;
                    if (kEx == 2) m2 = WMAX;
                    if (kEx == 3) m3 = WMAX;
                }
            } else {
                uint4 q4 = comp4[smin];
                m0 = (q4.x != cv) ? __float_as_uint(w4.x) : WMAX;
                m1 = (q4.y != cv) ? __float_as_uint(w4.y) : WMAX;
                m2 = (q4.z != cv) ? __float_as_uint(w4.z) : WMAX;
                m3 = (q4.w != cv) ? __float_as_uint(w4.w) : WMAX;
            }
            int k = (m0 == wmin) ? 0 : (m1 == wmin) ? 1 : (m2 == wmin) ? 2 : 3;
            unsigned umin = (unsigned)(c0 + smin * 4 + k);
            unsigned uv = (unsigned)v;
            unsigned lo = (umin < uv) ? ((umin << 9) | uv) : ((uv << 9) | umin);
            if (bestLo[cv] > lo) atomicMin(&bestLo[cv], lo);
        }
        __syncthreads();

        // hook
        unsigned hookp = 0, hw = WMAX, hlo = 0;
        if (tid < NV) {
            unsigned t = (unsigned)tid;
            hw = bestW[t];
            unsigned p = t;
            if (hw != WMAX) {
                hlo = bestLo[t];
                unsigned ci = comp[hlo >> 9], cj = comp[hlo & 511u];
                p = (ci == t) ? cj : ci;
            }
            hookp = p;
            parent[t] = p;
        }
        __syncthreads();

        // break 2-cycles
        if (tid < NV) {
            unsigned t = (unsigned)tid;
            unsigned p = parent[t];
            if (p != t && parent[p] == t && t < p) parent[t] = t;
        }
        __syncthreads();

        // accept + relabel walk
        bool take = false;
        if (tid < NV) {
            unsigned t = (unsigned)tid;
            if (hw != WMAX)
                take = !((bestW[hookp] == hw) && (bestLo[hookp] == hlo) && (hookp < t));
            if (take) {
                float a = __uint_as_float(hw);
                float b = Do[hlo];             // (i<<9)|j == i*512+j
                float d = a - b;
                contrib += d * d;
            }
            unsigned long long bal = __ballot(take);
            if ((tid & 63) == 0) waveAcc[tid >> 6] = __popcll(bal);
            unsigned r = comp[t];
            while (parent[r] != r) r = parent[r];
            comp[t] = r;
        }
        __syncthreads();

        if (tid < NV) { bestW[tid] = WMAX; bestLo[tid] = WMAX; }
        if (tid == 0) {
            int s = 0;
#pragma unroll
            for (int w = 0; w < 8; ++w) s += waveAcc[w];
            accTot += s;
            doneFlag = (accTot == NV - 1) ? 1 : 0;
        }
        __syncthreads();
        if (doneFlag) break;
    }

    if (!doneFlag) {
        // ============ renumber comps to dense ids [0,C), C<=128 ============
        if (tid < NV) parent[tid] = 0;
        __syncthreads();
        if (tid < NV) parent[comp[tid]] = 1;        // benign write races
        __syncthreads();
        unsigned bit = 0, rank = 0;
        if (tid < NV) {
            bit = parent[tid];
            ull m = __ballot(bit != 0);
            rank = (unsigned)__popcll(m & ((1ull << lane) - 1ull));
            if (lane == 0) waveSum[wid] = (unsigned)__popcll(m);
        }
        __syncthreads();
        if (tid == 0) {
            unsigned run = 0;
#pragma unroll
            for (int w = 0; w < 8; ++w) { unsigned t = waveSum[w]; waveSum[w] = run; run += t; }
        }
        __syncthreads();
        if (tid < NV && bit) bestW[tid] = waveSum[wid] + rank;  // root -> dense id
        __syncthreads();
        if (tid < NV) comp[tid] = bestW[comp[tid]];             // vertex -> dense id
        __syncthreads();

        // ============ contraction: R[a<b] = min key between comps ============
        for (int s = tid; s < 8128; s += 1024) R[s] = INF64;
        if (tid < 128) { cc[tid] = tid; bestK[tid] = INF64; }
        __syncthreads();
        {
            const unsigned cvd = comp[v];
            const int d = v - c0;
            const int sLo = (d < 0) ? 0 : (d >> 2);          // first group with u>v
            if (d < 256) {
                for (int s = sLo; s < 64; ++s) {
                    float4 w4 = rowp4[s];
                    uint4  q4 = comp4[s];
                    int u0 = c0 + s * 4;
                    unsigned wb[4] = {__float_as_uint(w4.x), __float_as_uint(w4.y),
                                      __float_as_uint(w4.z), __float_as_uint(w4.w)};
                    unsigned dq[4] = {q4.x, q4.y, q4.z, q4.w};
#pragma unroll
                    for (int k = 0; k < 4; ++k) {
                        int u = u0 + k;
                        if (u > v && dq[k] != cvd) {
                            unsigned a = min(cvd, dq[k]), b = max(cvd, dq[k]);
                            ull key = ((ull)wb[k] << 32) | (ull)(((unsigned)v << 9) | (unsigned)u);
                            atomicMin(&R[packIdx(a, b)], key);
                        }
                    }
                }
            }
        }
        __syncthreads();

        // ============ later rounds: entirely in LDS ============
        for (int rep = 0; rep < 8 && !doneFlag; ++rep) {
            // scan packed R: thread owns 16 consecutive b of row a
            {
                int a = tid >> 3;
                int b0 = (tid & 7) << 4;
                unsigned ca = cc[a];
                int base = packIdx((unsigned)a, 0);   // + b gives idx
#pragma unroll 4
                for (int m = 0; m < 16; ++m) {
                    int b = b0 + m;
                    if (b > a) {
                        ull e = R[base + b];
                        if (e != INF64) {
                            unsigned cb = cc[b];
                            if (cb != ca) {
                                atomicMin(&bestK[ca], e);
                                atomicMin(&bestK[cb], e);
                            }
                        }
                    }
                }
            }
            __syncthreads();

            // merge: wave 0, 2 comps/lane, fence-separated
            if (tid < 64) {
                ull e0, e1; unsigned p0, p1;
                {   // hook
                    unsigned t = (unsigned)lane;
                    e0 = bestK[t]; p0 = t;
                    if (e0 != INF64) {
                        unsigned lo = (unsigned)e0 & 0x3FFFFu;
                        unsigned ci = cc[comp[lo >> 9]], cj = cc[comp[lo & 511u]];
                        p0 = (ci == t) ? cj : ci;
                    }
                    cpar[t] = p0;
                    t = (unsigned)lane + 64u;
                    e1 = bestK[t]; p1 = t;
                    if (e1 != INF64) {
                        unsigned lo = (unsigned)e1 & 0x3FFFFu;
                        unsigned ci = cc[comp[lo >> 9]], cj = cc[comp[lo & 511u]];
                        p1 = (ci == t) ? cj : ci;
                    }
                    cpar[t] = p1;
                }
                __threadfence_block();
                {   // break 2-cycles
                    unsigned t = (unsigned)lane, p = cpar[t];
                    if (p != t && cpar[p] == t && t < p) cpar[t] = t;
                    t = (unsigned)lane + 64u; p = cpar[t];
                    if (p != t && cpar[p] == t && t < p) cpar[t] = t;
                }
                __threadfence_block();
                // accept (reads bestK) + relabel walk (reads cpar, writes own cc)
                bool take0 = false, take1 = false;
                if (e0 != INF64) take0 = !((bestK[p0] == e0) && (p0 < (unsigned)lane));
                if (e1 != INF64) take1 = !((bestK[p1] == e1) && (p1 < (unsigned)lane + 64u));
                if (take0) {
                    unsigned lo = (unsigned)e0 & 0x3FFFFu;
                    float a = __uint_as_float((unsigned)(e0 >> 32));
                    float d = a - Do[lo];
                    contrib2 += d * d;
                }
                if (take1) {
                    unsigned lo = (unsigned)e1 & 0x3FFFFu;
                    float a = __uint_as_float((unsigned)(e1 >> 32));
                    float d = a - Do[lo];
                    contrib2 += d * d;
                }
                int cnt = __popcll(__ballot(take0)) + __popcll(__ballot(take1));
                {
                    unsigned t = (unsigned)lane;
                    unsigned r = cc[t];
                    while (cpar[r] != r) r = cpar[r];
                    cc[t] = r;
                    t = (unsigned)lane + 64u;
                    r = cc[t];
                    while (cpar[r] != r) r = cpar[r];
                    cc[t] = r;
                }
                __threadfence_block();
                bestK[lane] = INF64; bestK[lane + 64] = INF64;
                if (lane == 0) {
                    accTot += cnt;
                    doneFlag = (accTot == NV - 1) ? 1 : 0;
                }
            }
            __syncthreads();
        }
    }

    // ================= deterministic reduction =================
#pragma unroll
    for (int off = 32; off >= 1; off >>= 1) contrib += __shfl_xor(contrib, off);
    if (lane == 0) red[wid] = contrib;          // 16 wave slots
    if (tid < 64) {
#pragma unroll
        for (int off = 32; off >= 1; off >>= 1) contrib2 += __shfl_xor(contrib2, off);
        if (lane == 0) red[16] = contrib2;
    }
    __syncthreads();
    if (tid == 0) {
        float s = 0.f;
#pragma unroll
        for (int w = 0; w < 17; ++w) s += red[w];
        partial[blk] = s;
    }
}

__global__ void final_add(const float* __restrict__ partial, float* __restrict__ out) {
    out[0] = partial[0] + partial[1];
}

} // namespace

extern "C" void kernel_launch(void* const* d_in, const int* in_sizes, int n_in,
                              void* d_out, int out_size, void* d_ws, size_t ws_size,
                              hipStream_t stream) {
    const float* d1 = (const float*)d_in[0];
    const float* d2 = (const float*)d_in[1];
    float* out = (float*)d_out;
    float* ws = (float*)d_ws;

    boruvka_loss<<<2, 1024, 0, stream>>>(d1, d2, ws); // writes ws[0], ws[1]
    final_add<<<1, 1, 0, stream>>>(ws, out);
}